// Round 6
// baseline (144.347 us; speedup 1.0000x reference)
//
#include <hip/hip_runtime.h>
#include <hip/hip_bf16.h>
#include <stdint.h>

// MoE: B=8, N=8192, D=128, C=128, E=8, K=2. Tokens T = 65536.
#define Dd 128
#define Cc 128
#define Ee 8
#define TM 64
#define NTOK 65536

using f32x4  = __attribute__((ext_vector_type(4))) float;
using short8 = __attribute__((ext_vector_type(8))) short;
typedef unsigned short u16;

__device__ inline u16 f2bf(float f) {
    union { __hip_bfloat16 h; u16 u; } cv;
    cv.h = __float2bfloat16(f);
    return cv.u;
}

// Pre-pass: expert_w [E][D][C] fp32 -> Wt [E][C][D] bf16 (transposed so MFMA
// B-fragments read contiguous k (=d) from LDS).
__global__ __launch_bounds__(256) void transpose_w(const float* __restrict__ w,
                                                   u16* __restrict__ wt) {
    int idx = blockIdx.x * 256 + threadIdx.x;   // flat (e,c,d), 131072 total
    int d = idx & 127;
    int c = (idx >> 7) & 127;
    int e = idx >> 14;
    wt[idx] = f2bf(w[(e << 14) + (d << 7) + c]);
}

// Fused: router (fp64 logits -> softmax -> top2 -> renorm gates) + dense
// per-expert MFMA with gated accumulation in registers.
__global__ __launch_bounds__(256, 3) void moe_main(
    const float* __restrict__ x,    // [T][D]
    const float* __restrict__ rw,   // [D][E]
    const float* __restrict__ rb,   // [E]
    const float* __restrict__ eb,   // [E][C]
    const u16*   __restrict__ wt,   // [E][C][D] bf16
    float*       __restrict__ out)  // [T][C]
{
    // 32 KB buffer shared by Xf (fp32 x-tile, used before expert loop) and
    // Ws (bf16 W^T tile, used inside expert loop).
    __shared__ __align__(16) unsigned char ldsA[Cc * Dd * 2];
    __shared__ __align__(16) u16 Xs[TM * Dd];     // 16 KB bf16 x-tile (swizzled)
    __shared__ float glg[TM * Ee];                // logits, then gates

    float* Xf = (float*)ldsA;
    u16*   Ws = (u16*)ldsA;

    const int tid = threadIdx.x;
    const int t0  = blockIdx.x * TM;

    // ---- stage Xf: 64 rows x 128 fp32, coalesced float4 ----
    {
        const float4* src = (const float4*)(x + (size_t)t0 * Dd);
        float4* dst = (float4*)Xf;
        #pragma unroll
        for (int j = 0; j < 8; ++j) dst[j * 256 + tid] = src[j * 256 + tid];
    }
    __syncthreads();

    // ---- router logits: 512 (token,expert) pairs, fp64 accumulation ----
    #pragma unroll
    for (int i = 0; i < 2; ++i) {
        int p  = tid * 2 + i;          // 0..511
        int tk = p >> 3, e = p & 7;
        double acc = (double)rb[e];
        const float* xr = Xf + tk * Dd;
        for (int d = 0; d < Dd; ++d)
            acc += (double)xr[d] * (double)rw[d * Ee + e];
        glg[p] = (float)acc;
    }

    // ---- convert Xf -> Xs bf16, XOR-swizzled 16B chunks ----
    #pragma unroll
    for (int j = 0; j < 4; ++j) {
        int fc = j * 256 + tid;        // 1024 chunks of 8 bf16
        int r = fc >> 4, c = fc & 15;
        const float4* s = (const float4*)(Xf + r * Dd + c * 8);
        float4 a = s[0], b = s[1];
        short8 v;
        v[0] = (short)f2bf(a.x); v[1] = (short)f2bf(a.y);
        v[2] = (short)f2bf(a.z); v[3] = (short)f2bf(a.w);
        v[4] = (short)f2bf(b.x); v[5] = (short)f2bf(b.y);
        v[6] = (short)f2bf(b.z); v[7] = (short)f2bf(b.w);
        *(short8*)&Xs[r * Dd + (((c ^ (r & 7)) & 15) << 3)] = v;
    }
    __syncthreads();

    // ---- softmax + top2 + renormalized gates (thread per token) ----
    if (tid < TM) {
        float l[Ee];
        #pragma unroll
        for (int e = 0; e < Ee; ++e) l[e] = glg[tid * Ee + e];
        int e0 = 0;
        #pragma unroll
        for (int e = 1; e < Ee; ++e) if (l[e] > l[e0]) e0 = e;
        int e1 = (e0 == 0) ? 1 : 0;
        #pragma unroll
        for (int e = 0; e < Ee; ++e)
            if (e != e0 && l[e] > l[e1]) e1 = e;
        float g1 = __expf(l[e1] - l[e0]);   // p1/p0 (softmax denom cancels)
        float s  = 1.0f + g1;
        float g0 = 1.0f / s; g1 = g1 / s;
        #pragma unroll
        for (int e = 0; e < Ee; ++e) glg[tid * Ee + e] = 0.0f;
        glg[tid * Ee + e0] = g0;
        glg[tid * Ee + e1] = g1;
    }

    // ---- expert loop: stage W^T[e] to LDS, MFMA 64x128, gated accumulate ----
    const int lane = tid & 63;
    const int wv   = tid >> 6;
    const int m0   = (wv >> 1) * 32;   // wave -> 32x64 sub-tile
    const int n0   = (wv & 1) * 64;
    const int ln15 = lane & 15;
    const int kg   = lane >> 4;

    f32x4 oacc[2][4] = {};

    for (int e = 0; e < Ee; ++e) {
        __syncthreads();               // prior reads of Ws/Xf done
        {
            const u16* src = wt + ((size_t)e << 14);
            #pragma unroll
            for (int j = 0; j < 8; ++j) {
                int fc = j * 256 + tid;            // 2048 chunks of 8 bf16
                int r = fc >> 4, c = fc & 15;
                short8 v = *(const short8*)(src + (fc << 3));
                *(short8*)&Ws[r * Dd + (((c ^ (r & 7)) & 15) << 3)] = v;
            }
        }
        __syncthreads();

        f32x4 acc[2][4] = {};
        #pragma unroll
        for (int ks = 0; ks < 4; ++ks) {
            short8 af[2], bfr[4];
            #pragma unroll
            for (int mi = 0; mi < 2; ++mi) {
                int r = m0 + mi * 16 + ln15;
                af[mi] = *(const short8*)
                    &Xs[r * Dd + ((((ks * 4 + kg) ^ (r & 7)) & 15) << 3)];
            }
            #pragma unroll
            for (int ni = 0; ni < 4; ++ni) {
                int r = n0 + ni * 16 + ln15;
                bfr[ni] = *(const short8*)
                    &Ws[r * Dd + ((((ks * 4 + kg) ^ (r & 7)) & 15) << 3)];
            }
            #pragma unroll
            for (int mi = 0; mi < 2; ++mi)
                #pragma unroll
                for (int ni = 0; ni < 4; ++ni)
                    acc[mi][ni] = __builtin_amdgcn_mfma_f32_16x16x32_bf16(
                        af[mi], bfr[ni], acc[mi][ni], 0, 0, 0);
        }

        // gated accumulate: out += g[t][e] * (acc + bias[e][c])
        #pragma unroll
        for (int mi = 0; mi < 2; ++mi) {
            #pragma unroll
            for (int r = 0; r < 4; ++r) {
                float g = glg[(m0 + mi * 16 + kg * 4 + r) * Ee + e];
                #pragma unroll
                for (int ni = 0; ni < 4; ++ni) {
                    float b = eb[e * Cc + n0 + ni * 16 + ln15];
                    oacc[mi][ni][r] += g * (acc[mi][ni][r] + b);
                }
            }
        }
    }

    // ---- write out ----
    #pragma unroll
    for (int mi = 0; mi < 2; ++mi)
        #pragma unroll
        for (int r = 0; r < 4; ++r) {
            size_t row = (size_t)(t0 + m0 + mi * 16 + kg * 4 + r);
            #pragma unroll
            for (int ni = 0; ni < 4; ++ni)
                out[row * Cc + n0 + ni * 16 + ln15] = oacc[mi][ni][r];
        }
}

extern "C" void kernel_launch(void* const* d_in, const int* in_sizes, int n_in,
                              void* d_out, int out_size, void* d_ws, size_t ws_size,
                              hipStream_t stream) {
    const float* x  = (const float*)d_in[0];
    const float* rw = (const float*)d_in[1];
    const float* rb = (const float*)d_in[2];
    const float* ew = (const float*)d_in[3];
    const float* eb = (const float*)d_in[4];
    float* out = (float*)d_out;
    u16* wt = (u16*)d_ws;                       // 256 KB bf16 W^T

    transpose_w<<<dim3(512), dim3(256), 0, stream>>>(ew, wt);
    moe_main<<<dim3(NTOK / TM), dim3(256), 0, stream>>>(x, rw, rb, eb, wt, out);
}